// Round 6
// baseline (361.805 us; speedup 1.0000x reference)
//
#include <hip/hip_runtime.h>

// LIF dual forward: x [T,B,N,C] f32, decay scalar.
// out = concat(spikes [T,B,N,C] f32, vpool [T,B,C] f32) flat.
//
// R11: FUSE STAGE2 VIA ATOMICS. Remaining controllable bytes were the
// partial round-trip (16.8 MB W by stage1 + 16.8 MB R by stage2 + 1 MB
// vpool W + one dispatch + dirty-residue drag on the next harness fill).
// Now: tiny zero-kernel clears the poisoned vpool region (1 MB), then
// stage1 LDS-reduces across its 4 waves as before and atomicAdds the
// (1/196)-scaled block contribution directly into vpool (4096 fp32
// atomics/block, 4.2M total, 16-way contention -- L2 atomic units,
// device-scope by default so cross-XCD safe). d_ws no longer used.
// R10 (kept): spikes stored NON-TEMPORAL (write-once, never re-read);
// leaving L3 clean bought ~10 us of harness-fill time.
// R9  (kept): two-row pairing, 32-bit byte offsets.
// R8  (kept): 1024 blocks x 256 thr, __launch_bounds__(256,4) = exactly
// 4 blocks/CU, zero tail; 196 rows = 4 groups x13 + 12 x12.
// R7  (kept): reduction tc-loop fully unrolled -> vpsum statically
// indexed, stays in VGPRs (rule #20).
// R5  (kept): x loads NON-TEMPORAL.
constexpr int T   = 16;
constexpr int B   = 32;
constexpr int N   = 196;
constexpr int C   = 512;
constexpr int C4  = C / 4;     // 128 float4 columns
constexpr int TX  = 64;        // c4 lanes per block (one wave per ty row)
constexpr int TY  = 4;         // rows in flight per block
constexpr int NGRP = 16;       // row-groups per (b, c-half): 4x13 + 12x12

typedef float f32x4 __attribute__((ext_vector_type(4)));

__device__ __forceinline__ void lif_step(float d, f32x4 xt, f32x4& v, f32x4& s) {
  v.x = d * v.x + xt.x;
  v.y = d * v.y + xt.y;
  v.z = d * v.z + xt.z;
  v.w = d * v.w + xt.w;
  s.x = (v.x >= 1.0f) ? 1.0f : 0.0f;
  s.y = (v.y >= 1.0f) ? 1.0f : 0.0f;
  s.z = (v.z >= 1.0f) ? 1.0f : 0.0f;
  s.w = (v.w >= 1.0f) ? 1.0f : 0.0f;
}

__device__ __forceinline__ void lif_reset(f32x4& v) {
  v.x = (v.x >= 1.0f) ? 0.0f : v.x;
  v.y = (v.y >= 1.0f) ? 0.0f : v.y;
  v.z = (v.z >= 1.0f) ? 0.0f : v.z;
  v.w = (v.w >= 1.0f) ? 0.0f : v.w;
}

// Clear the poisoned vpool region (harness poisons d_out every iteration).
__global__ __launch_bounds__(256) void vpool_zero(f32x4* __restrict__ vp) {
  vp[(size_t)blockIdx.x * 256 + threadIdx.x] = (f32x4)(0.f);
}

__global__ __launch_bounds__(TX * TY, 4) void lif_stage1(
    const f32x4* __restrict__ x,
    const float* __restrict__ decay,
    f32x4* __restrict__ spikes,
    float* __restrict__ vpool) {            // [T][B][C] f32, atomic target
  __shared__ f32x4 red[TY][4][TX];          // 16 KB (4 blocks/CU -> 64 KB)

  const int tx = threadIdx.x;               // 0..63
  const int ty = threadIdx.y;               // 0..3
  const int cc = blockIdx.x;                // 0..1  (c-half)
  const int gi = blockIdx.y;                // 0..15 (row group)
  const int b  = blockIdx.z;                // 0..31

  const int c4 = cc * TX + tx;              // 0..127
  const float d = decay[0];

  // 196 = 16*12 + 4: groups 0..3 get 13 rows, 4..15 get 12.
  const int start = gi * 12 + (gi < 4 ? gi : 4);
  const int count = 12 + (gi < 4 ? 1 : 0);

  f32x4 vpsum[T];
#pragma unroll
  for (int t = 0; t < T; ++t) vpsum[t] = (f32x4)(0.f);

  // 32-bit byte offsets: x / spikes are 205.5 MB each, fits u32.
  const char* xb = (const char*)x;
  char*       sb = (char*)spikes;
  const unsigned tstride_b = (unsigned)(B * N * C4) * 16u;  // bytes per t
  const unsigned rstride_b = (unsigned)(TY * C4) * 16u;     // bytes per +TY rows

  int n = start + ty;
  const int nEnd = start + count;

  // Pairs of rows (n, n+TY): two independent recurrence chains per wave.
  for (; n + TY < nEnd; n += 2 * TY) {
    unsigned off0 = (((unsigned)b * N + n) * C4 + c4) * 16u;
    unsigned off1 = off0 + rstride_b;
    f32x4 va = (f32x4)(0.f), vb = (f32x4)(0.f);

#pragma unroll
    for (int t = 0; t < T; ++t) {
      f32x4 xa = __builtin_nontemporal_load((const f32x4*)(xb + off0));
      f32x4 xc = __builtin_nontemporal_load((const f32x4*)(xb + off1));

      f32x4 sa, sc;
      lif_step(d, xa, va, sa);
      lif_step(d, xc, vb, sc);

      vpsum[t].x += va.x + vb.x;
      vpsum[t].y += va.y + vb.y;
      vpsum[t].z += va.z + vb.z;
      vpsum[t].w += va.w + vb.w;

      // Spikes are write-once, never re-read: stream past L3 (R10).
      __builtin_nontemporal_store(sa, (f32x4*)(sb + off0));
      __builtin_nontemporal_store(sc, (f32x4*)(sb + off1));
      lif_reset(va);
      lif_reset(vb);

      off0 += tstride_b;
      off1 += tstride_b;
    }
  }

  // Leftover single row (waves with an odd row count).
  if (n < nEnd) {
    unsigned off0 = (((unsigned)b * N + n) * C4 + c4) * 16u;
    f32x4 va = (f32x4)(0.f);
#pragma unroll
    for (int t = 0; t < T; ++t) {
      f32x4 xa = __builtin_nontemporal_load((const f32x4*)(xb + off0));
      f32x4 sa;
      lif_step(d, xa, va, sa);
      vpsum[t].x += va.x;
      vpsum[t].y += va.y;
      vpsum[t].z += va.z;
      vpsum[t].w += va.w;
      __builtin_nontemporal_store(sa, (f32x4*)(sb + off0));
      lif_reset(va);
      off0 += tstride_b;
    }
  }

  // Reduce vpsum over the 4 ty waves via LDS, 4 t per round (fully
  // unrolled so vpsum stays in VGPRs -- R7), then atomicAdd the scaled
  // block contribution straight into vpool (R11).
  const float inv_n = 1.0f / (float)N;
  const int flat = ty * TX + tx;            // 0..255
  const int jj   = flat >> 6;               // 0..3
  const int col  = flat & 63;               // 0..63
#pragma unroll
  for (int tc = 0; tc < T; tc += 4) {
#pragma unroll
    for (int j = 0; j < 4; ++j) red[ty][j][tx] = vpsum[tc + j];
    __syncthreads();
    {
      f32x4 a = red[0][jj][col];
#pragma unroll
      for (int k = 1; k < TY; ++k) {
        f32x4 r2 = red[k][jj][col];
        a.x += r2.x; a.y += r2.y; a.z += r2.z; a.w += r2.w;
      }
      const int t = tc + jj;
      float* vp = vpool + ((((size_t)t * B + b) * C4) + (cc * TX + col)) * 4;
      atomicAdd(vp + 0, a.x * inv_n);
      atomicAdd(vp + 1, a.y * inv_n);
      atomicAdd(vp + 2, a.z * inv_n);
      atomicAdd(vp + 3, a.w * inv_n);
    }
    __syncthreads();
  }
}

extern "C" void kernel_launch(void* const* d_in, const int* in_sizes, int n_in,
                              void* d_out, int out_size, void* d_ws, size_t ws_size,
                              hipStream_t stream) {
  const f32x4* x      = (const f32x4*)d_in[0];
  const float* decay  = (const float*)d_in[1];

  float* out = (float*)d_out;
  const size_t spike_elems = (size_t)T * B * N * C;   // 51,380,224

  f32x4* spikes  = (f32x4*)out;
  float* vpool   = out + spike_elems;      // T*B*C floats = 1 MB
  f32x4* vpool4  = (f32x4*)vpool;          // 65536 f32x4

  // Zero poisoned vpool (same stream -> ordered before stage1's atomics).
  vpool_zero<<<dim3((T * B * C / 4) / 256), dim3(256), 0, stream>>>(vpool4);

  dim3 block1(TX, TY);                     // 64 x 4 = 256 threads (4 waves)
  dim3 grid1(2, NGRP, B);                  // 2 x 16 x 32 = 1024 blocks = 4/CU exact
  lif_stage1<<<grid1, block1, 0, stream>>>(x, decay, spikes, vpool);
}

// Round 7
// 341.652 us; speedup vs baseline: 1.0590x; 1.0590x over previous
//
#include <hip/hip_runtime.h>

// LIF dual forward: x [T,B,N,C] f32, decay scalar.
// out = concat(spikes [T,B,N,C] f32, vpool [T,B,C] f32) flat.
//
// R12: REVERT TO R10 (best: 342.9 us). R11's atomic fusion of stage2
// regressed +19 us: 4.2M device-scope fp32 atomicAdds (16-way contention)
// cost far more than the 33.6 MB partial round-trip they replaced (which
// was largely L2/L3-absorbed) plus stage2's ~3.5 us. Lesson recorded:
// contended global atomics lose to a cache-friendly two-pass reduction
// at this scale. This file is R10 verbatim.
// R10: spikes stored NON-TEMPORAL (write-once, never re-read). Leaving
// L3 clean bought ~10 us of next-iteration harness poison-fill time and
// preserves cross-iteration x residency in L3.
// R9 (kept): two-row pairing (2 independent recurrence/load chains per
// wave), 32-bit byte offsets (SGPR base + u32 voffset).
// R8 (kept): 1024 blocks x 256 thr, __launch_bounds__(256,4) = exactly
// 4 blocks/CU, zero tail; 196 rows = 4 groups x13 + 12 x12.
// R7 (kept): reduction tc-loop fully unrolled -> vpsum statically
// indexed, stays in VGPRs (rule #20).
// R5 (kept): x loads NON-TEMPORAL (don't evict poisoned d_out lines /
// don't pollute L3 with a once-read stream).
constexpr int T   = 16;
constexpr int B   = 32;
constexpr int N   = 196;
constexpr int C   = 512;
constexpr int C4  = C / 4;     // 128 float4 columns
constexpr int TX  = 64;        // c4 lanes per block (one wave per ty row)
constexpr int TY  = 4;         // rows in flight per block
constexpr int NGRP = 16;       // row-groups per (b, c-half): 4x13 + 12x12
constexpr int PCHUNK_F4 = T * B * C4;   // f32x4 per partial chunk = 65536

typedef float f32x4 __attribute__((ext_vector_type(4)));

__device__ __forceinline__ void lif_step(float d, f32x4 xt, f32x4& v, f32x4& s) {
  v.x = d * v.x + xt.x;
  v.y = d * v.y + xt.y;
  v.z = d * v.z + xt.z;
  v.w = d * v.w + xt.w;
  s.x = (v.x >= 1.0f) ? 1.0f : 0.0f;
  s.y = (v.y >= 1.0f) ? 1.0f : 0.0f;
  s.z = (v.z >= 1.0f) ? 1.0f : 0.0f;
  s.w = (v.w >= 1.0f) ? 1.0f : 0.0f;
}

__device__ __forceinline__ void lif_reset(f32x4& v) {
  v.x = (v.x >= 1.0f) ? 0.0f : v.x;
  v.y = (v.y >= 1.0f) ? 0.0f : v.y;
  v.z = (v.z >= 1.0f) ? 0.0f : v.z;
  v.w = (v.w >= 1.0f) ? 0.0f : v.w;
}

__global__ __launch_bounds__(TX * TY, 4) void lif_stage1(
    const f32x4* __restrict__ x,
    const float* __restrict__ decay,
    f32x4* __restrict__ spikes,
    f32x4* __restrict__ partial) {          // [NGRP][T][B][C4] f32x4
  __shared__ f32x4 red[TY][4][TX];          // 16 KB (4 blocks/CU -> 64 KB)

  const int tx = threadIdx.x;               // 0..63
  const int ty = threadIdx.y;               // 0..3
  const int cc = blockIdx.x;                // 0..1  (c-half)
  const int gi = blockIdx.y;                // 0..15 (row group)
  const int b  = blockIdx.z;                // 0..31

  const int c4 = cc * TX + tx;              // 0..127
  const float d = decay[0];

  // 196 = 16*12 + 4: groups 0..3 get 13 rows, 4..15 get 12.
  const int start = gi * 12 + (gi < 4 ? gi : 4);
  const int count = 12 + (gi < 4 ? 1 : 0);

  f32x4 vpsum[T];
#pragma unroll
  for (int t = 0; t < T; ++t) vpsum[t] = (f32x4)(0.f);

  // 32-bit byte offsets: x / spikes are 205.5 MB each, fits u32.
  const char* xb = (const char*)x;
  char*       sb = (char*)spikes;
  const unsigned tstride_b = (unsigned)(B * N * C4) * 16u;  // bytes per t
  const unsigned rstride_b = (unsigned)(TY * C4) * 16u;     // bytes per +TY rows

  int n = start + ty;
  const int nEnd = start + count;

  // Pairs of rows (n, n+TY): two independent recurrence chains per wave.
  for (; n + TY < nEnd; n += 2 * TY) {
    unsigned off0 = (((unsigned)b * N + n) * C4 + c4) * 16u;
    unsigned off1 = off0 + rstride_b;
    f32x4 va = (f32x4)(0.f), vb = (f32x4)(0.f);

#pragma unroll
    for (int t = 0; t < T; ++t) {
      f32x4 xa = __builtin_nontemporal_load((const f32x4*)(xb + off0));
      f32x4 xc = __builtin_nontemporal_load((const f32x4*)(xb + off1));

      f32x4 sa, sc;
      lif_step(d, xa, va, sa);
      lif_step(d, xc, vb, sc);

      vpsum[t].x += va.x + vb.x;
      vpsum[t].y += va.y + vb.y;
      vpsum[t].z += va.z + vb.z;
      vpsum[t].w += va.w + vb.w;

      // Spikes are write-once, never re-read: stream past L3 (R10).
      __builtin_nontemporal_store(sa, (f32x4*)(sb + off0));
      __builtin_nontemporal_store(sc, (f32x4*)(sb + off1));
      lif_reset(va);
      lif_reset(vb);

      off0 += tstride_b;
      off1 += tstride_b;
    }
  }

  // Leftover single row (waves with an odd row count).
  if (n < nEnd) {
    unsigned off0 = (((unsigned)b * N + n) * C4 + c4) * 16u;
    f32x4 va = (f32x4)(0.f);
#pragma unroll
    for (int t = 0; t < T; ++t) {
      f32x4 xa = __builtin_nontemporal_load((const f32x4*)(xb + off0));
      f32x4 sa;
      lif_step(d, xa, va, sa);
      vpsum[t].x += va.x;
      vpsum[t].y += va.y;
      vpsum[t].z += va.z;
      vpsum[t].w += va.w;
      __builtin_nontemporal_store(sa, (f32x4*)(sb + off0));
      lif_reset(va);
      off0 += tstride_b;
    }
  }

  // Reduce vpsum over the 4 ty waves via LDS, 4 t per round.
  // FULLY UNROLLED (tc is compile-time) so vpsum indices are static and
  // the array stays in VGPRs (R7).
  const int flat = ty * TX + tx;            // 0..255
  const int jj   = flat >> 6;               // 0..3
  const int col  = flat & 63;               // 0..63
#pragma unroll
  for (int tc = 0; tc < T; tc += 4) {
#pragma unroll
    for (int j = 0; j < 4; ++j) red[ty][j][tx] = vpsum[tc + j];
    __syncthreads();
    {
      f32x4 a = red[0][jj][col];
#pragma unroll
      for (int k = 1; k < TY; ++k) {
        f32x4 r2 = red[k][jj][col];
        a.x += r2.x; a.y += r2.y; a.z += r2.z; a.w += r2.w;
      }
      const int t = tc + jj;
      const size_t pidx = (size_t)gi * PCHUNK_F4 +
                          ((size_t)t * B + b) * C4 + (cc * TX + col);
      partial[pidx] = a;    // PLAIN store: stage2 re-reads this, keep in L2/L3
    }
    __syncthreads();
  }
}

__global__ __launch_bounds__(256) void lif_stage2(
    const f32x4* __restrict__ partial,      // [NGRP][T*B*C4] f32x4
    f32x4* __restrict__ vpool) {            // [T*B*C4] f32x4
  const int gid = blockIdx.x * 256 + threadIdx.x;   // 0..65535
  const float inv_n = 1.0f / (float)N;
  f32x4 a = partial[gid];
#pragma unroll
  for (int k = 1; k < NGRP; ++k) {
    f32x4 r = partial[(size_t)k * PCHUNK_F4 + gid];
    a.x += r.x; a.y += r.y; a.z += r.z; a.w += r.w;
  }
  a.x *= inv_n; a.y *= inv_n; a.z *= inv_n; a.w *= inv_n;
  vpool[gid] = a;
}

extern "C" void kernel_launch(void* const* d_in, const int* in_sizes, int n_in,
                              void* d_out, int out_size, void* d_ws, size_t ws_size,
                              hipStream_t stream) {
  const f32x4* x      = (const f32x4*)d_in[0];
  const float* decay  = (const float*)d_in[1];

  float* out = (float*)d_out;
  const size_t spike_elems = (size_t)T * B * N * C;   // 51,380,224

  f32x4* spikes  = (f32x4*)out;
  f32x4* vpool   = (f32x4*)(out + spike_elems);
  f32x4* partial = (f32x4*)d_ws;   // needs NGRP*T*B*C floats = 16.8 MB

  dim3 block1(TX, TY);                     // 64 x 4 = 256 threads (4 waves)
  dim3 grid1(2, NGRP, B);                  // 2 x 16 x 32 = 1024 blocks = 4/CU exact
  lif_stage1<<<grid1, block1, 0, stream>>>(x, decay, spikes, partial);

  lif_stage2<<<dim3(PCHUNK_F4 / 256), dim3(256), 0, stream>>>(partial, vpool);
}